// Round 2
// baseline (223.080 us; speedup 1.0000x reference)
//
#include <hip/hip_runtime.h>

#define NPTS 2048
#define HARD_COS 0.9914448613738104f  // cos(7.5 deg); ang>15deg <=> clipped |dot| < this

// ws layout: gt_rot float4[B][NPTS] at offset 0   {gx, gy, gz, |g|^2}

__device__ __forceinline__ float smooth_l1(float x) {
    float ax = fabsf(x);
    return (ax < 1.0f) ? 0.5f * x * x : ax - 0.5f;
}

// K1: per-block ballot-derived cls, rotate gt cloud into ws. Block (0,0) zeroes out
// (harness poisons d_out). grid (NPTS/256, B).
__global__ __launch_bounds__(256) void pm_rotgt(const float* __restrict__ tgt,
                                                const float* __restrict__ wgt,
                                                const float* __restrict__ pts,
                                                float* __restrict__ ws,
                                                float* __restrict__ out,
                                                int C) {
    const int b = blockIdx.y;
    const int tid = threadIdx.x;
    if (blockIdx.x == 0 && b == 0 && tid == 0) out[0] = 0.0f;

    // first class with weight>0 via wave ballot (C=22 <= 64 lanes)
    const int lane = tid & 63;
    bool has = (lane < C) && (wgt[(size_t)b * 4 * C + (size_t)lane * 4] > 0.0f);
    unsigned long long m = __ballot(has);
    if (m == 0ull) return;                       // invalid sample: contributes 0
    const int cls = (int)__ffsll((unsigned long long)m) - 1;

    const float* qg = tgt + (size_t)b * 4 * C + (size_t)cls * 4;
    const float gw = qg[0], gx = qg[1], gy = qg[2], gz = qg[3];
    const float m0 = 1.f - 2.f * (gy * gy + gz * gz);
    const float m1 = 2.f * (gx * gy - gz * gw);
    const float m2 = 2.f * (gx * gz + gy * gw);
    const float m3 = 2.f * (gx * gy + gz * gw);
    const float m4 = 1.f - 2.f * (gx * gx + gz * gz);
    const float m5 = 2.f * (gy * gz - gx * gw);
    const float m6 = 2.f * (gx * gz - gy * gw);
    const float m7 = 2.f * (gy * gz + gx * gw);
    const float m8 = 1.f - 2.f * (gx * gx + gy * gy);

    const float* p = pts + (size_t)cls * NPTS * 3;
    float4* dst = (float4*)ws + (size_t)b * NPTS;
    const int i = blockIdx.x * 256 + tid;
    const float x = p[i * 3 + 0], y = p[i * 3 + 1], z = p[i * 3 + 2];
    const float ax = m0 * x + m1 * y + m2 * z;
    const float ay = m3 * x + m4 * y + m5 * z;
    const float az = m6 * x + m7 * y + m8 * z;
    const float w = ax * ax + ay * ay + az * az;   // same expr as prior pm_rotate
    dst[i] = make_float4(ax, ay, az, w);
}

// K2: per-block redundant meta (ballot + quat dot), rotate own pred in-register,
// scan all 2048 gt via wave-uniform loads (L1-resident 32 KB), smooth-L1, reduce.
// grid (NPTS/256, B).
__global__ __launch_bounds__(256) void pm_loss(const float* __restrict__ pred,
                                               const float* __restrict__ tgt,
                                               const float* __restrict__ wgt,
                                               const float* __restrict__ pts,
                                               const float* __restrict__ sym,
                                               const float* __restrict__ ws,
                                               float* __restrict__ out,
                                               int C, float inv_bp) {
    __shared__ float partial[4];
    const int b = blockIdx.y;
    const int tid = threadIdx.x;
    const int lane = tid & 63;

    bool has = (lane < C) && (wgt[(size_t)b * 4 * C + (size_t)lane * 4] > 0.0f);
    unsigned long long mm = __ballot(has);
    float acc = 0.0f;

    if (mm != 0ull) {
        const int cls = (int)__ffsll((unsigned long long)mm) - 1;
        const float* qp = pred + (size_t)b * 4 * C + (size_t)cls * 4;
        const float* qg = tgt  + (size_t)b * 4 * C + (size_t)cls * 4;
        const float pw = qp[0], px = qp[1], py = qp[2], pz = qp[3];
        const float gw = qg[0], gx = qg[1], gy = qg[2], gz = qg[3];

        // R_pred (identical expressions to prior pm_prep -> identical bits)
        const float r0 = 1.f - 2.f * (py * py + pz * pz);
        const float r1 = 2.f * (px * py - pz * pw);
        const float r2 = 2.f * (px * pz + py * pw);
        const float r3 = 2.f * (px * py + pz * pw);
        const float r4 = 1.f - 2.f * (px * px + pz * pz);
        const float r5 = 2.f * (py * pz - px * pw);
        const float r6 = 2.f * (px * pz - py * pw);
        const float r7 = 2.f * (py * pz + px * pw);
        const float r8 = 1.f - 2.f * (px * px + py * py);

        float dot = fabsf(pw * gw + px * gx + py * gy + pz * gz);
        dot = fminf(fmaxf(dot, 0.0f), 1.0f);
        const bool uc = (sym[cls] > 0.0f) && (dot < HARD_COS);

        // rotate own pred point in-register
        const int p = blockIdx.x * 256 + tid;
        const float* pp = pts + (size_t)cls * NPTS * 3 + (size_t)p * 3;
        const float x = pp[0], y = pp[1], z = pp[2];
        const float ppx = r0 * x + r1 * y + r2 * z;
        const float ppy = r3 * x + r4 * y + r5 * z;
        const float ppz = r6 * x + r7 * y + r8 * z;

        const float4* gtb = (const float4*)ws + (size_t)b * NPTS;
        float mx, my, mz;
        if (uc) {
            const float nx = -2.0f * ppx, ny = -2.0f * ppy, nz = -2.0f * ppz;
            float bd = 3.4e38f;
            int bj = 0;
#pragma unroll 8
            for (int j = 0; j < NPTS; ++j) {
                // gtb + j is wave-uniform -> scalar/broadcast load, L1-resident
                float4 g = gtb[j];
                float d = __fmaf_rn(nx, g.x,
                          __fmaf_rn(ny, g.y,
                          __fmaf_rn(nz, g.z, g.w)));
                if (d < bd) { bd = d; bj = j; }   // strict <: global first-min
            }
            float4 g = gtb[bj];
            mx = g.x; my = g.y; mz = g.z;
        } else {
            float4 g = gtb[p];
            mx = g.x; my = g.y; mz = g.z;
        }
        acc = smooth_l1(ppx - mx) + smooth_l1(ppy - my) + smooth_l1(ppz - mz);
    }

    for (int off = 32; off > 0; off >>= 1) acc += __shfl_down(acc, off);
    if ((tid & 63) == 0) partial[tid >> 6] = acc;
    __syncthreads();
    if (tid == 0) {
        float s = partial[0] + partial[1] + partial[2] + partial[3];
        atomicAdd(out, s * inv_bp);
    }
}

extern "C" void kernel_launch(void* const* d_in, const int* in_sizes, int n_in,
                              void* d_out, int out_size, void* d_ws, size_t ws_size,
                              hipStream_t stream) {
    const float* pred = (const float*)d_in[0];
    const float* tgt  = (const float*)d_in[1];
    const float* wgt  = (const float*)d_in[2];
    const float* pts  = (const float*)d_in[3];
    const float* sym  = (const float*)d_in[4];
    float* out = (float*)d_out;
    float* ws  = (float*)d_ws;

    const int C = in_sizes[4];
    const int B = in_sizes[0] / (4 * C);

    dim3 grid(NPTS / 256, B);
    pm_rotgt<<<grid, 256, 0, stream>>>(tgt, wgt, pts, ws, out, C);
    pm_loss<<<grid, 256, 0, stream>>>(pred, tgt, wgt, pts, sym, ws, out, C,
                                      1.0f / (float)(B * NPTS));
}

// Round 3
// 89.126 us; speedup vs baseline: 2.5030x; 2.5030x over previous
//
#include <hip/hip_runtime.h>

#define NPTS 2048
#define PPB 128                 // preds per block in pm_scan (2 per lane)
#define HARD_COS 0.9914448613738104f  // cos(7.5 deg); ang>15deg <=> clipped |dot| < this

// ws layout: pred_rot float4[B][NPTS] at 0 {x,y,z,0};
//            gt_rot   float4[B][NPTS] at gt_off floats {x,y,z,|g|^2}

__device__ __forceinline__ float smooth_l1(float x) {
    float ax = fabsf(x);
    return (ax < 1.0f) ? 0.5f * x * x : ax - 0.5f;
}

// K1: grid (2, B). side 0 rotates pred cloud, side 1 rotates gt cloud (+|g|^2).
// cls derived per block via wave ballot (C=22 <= 64 lanes). Block (0,0) zeroes out.
__global__ __launch_bounds__(256) void pm_rot(const float* __restrict__ pred,
                                              const float* __restrict__ tgt,
                                              const float* __restrict__ wgt,
                                              const float* __restrict__ pts,
                                              float* __restrict__ ws,
                                              float* __restrict__ out,
                                              int C, int gt_off) {
    const int b = blockIdx.y;
    const int side = blockIdx.x;
    const int tid = threadIdx.x;
    if (side == 0 && b == 0 && tid == 0) out[0] = 0.0f;

    const int lane = tid & 63;
    bool has = (lane < C) && (wgt[(size_t)b * 4 * C + (size_t)lane * 4] > 0.0f);
    unsigned long long m = __ballot(has);
    if (m == 0ull) return;                       // invalid sample: contributes 0
    const int cls = (int)__ffsll((unsigned long long)m) - 1;

    const float* q = (side == 0 ? pred : tgt) + (size_t)b * 4 * C + (size_t)cls * 4;
    const float qw = q[0], qx = q[1], qy = q[2], qz = q[3];
    const float m0 = 1.f - 2.f * (qy * qy + qz * qz);
    const float m1 = 2.f * (qx * qy - qz * qw);
    const float m2 = 2.f * (qx * qz + qy * qw);
    const float m3 = 2.f * (qx * qy + qz * qw);
    const float m4 = 1.f - 2.f * (qx * qx + qz * qz);
    const float m5 = 2.f * (qy * qz - qx * qw);
    const float m6 = 2.f * (qx * qz - qy * qw);
    const float m7 = 2.f * (qy * qz + qx * qw);
    const float m8 = 1.f - 2.f * (qx * qx + qy * qy);

    const float* p = pts + (size_t)cls * NPTS * 3;
    float4* dst = (float4*)(ws + (side == 0 ? 0 : (size_t)gt_off)) + (size_t)b * NPTS;
#pragma unroll
    for (int r = 0; r < 8; ++r) {
        const int i = r * 256 + tid;
        const float x = p[i * 3 + 0], y = p[i * 3 + 1], z = p[i * 3 + 2];
        const float ax = m0 * x + m1 * y + m2 * z;
        const float ay = m3 * x + m4 * y + m5 * z;
        const float az = m6 * x + m7 * y + m8 * z;
        const float w = (side == 0) ? 0.0f : (ax * ax + ay * ay + az * az);
        dst[i] = make_float4(ax, ay, az, w);
    }
}

// K2: grid (NPTS/PPB=16, B), 256 thr. Block owns 128 preds (2/lane, all 4 waves
// hold the same preds). gt staged in LDS; wave w scans gt-quarter w with
// per-wave-uniform (broadcast, conflict-free) ds reads. Block-internal combine in
// ascending quarter order with strict < == exact global first-min. Wave 0 gathers
// winners, smooth-L1, shfl-reduce, one atomicAdd per block.
__global__ __launch_bounds__(256) void pm_scan(const float* __restrict__ pred,
                                               const float* __restrict__ tgt,
                                               const float* __restrict__ wgt,
                                               const float* __restrict__ sym,
                                               const float* __restrict__ ws,
                                               float* __restrict__ out,
                                               int C, int gt_off, float inv_bp) {
    __shared__ float4 gls[NPTS];   // 32 KB
    __shared__ float  sbd[512];
    __shared__ int    sbj[512];
    const int b = blockIdx.y;
    const int tid = threadIdx.x;
    const int lane = tid & 63;

    bool has = (lane < C) && (wgt[(size_t)b * 4 * C + (size_t)lane * 4] > 0.0f);
    unsigned long long mm = __ballot(has);
    if (mm == 0ull) return;
    const int cls = (int)__ffsll((unsigned long long)mm) - 1;

    const float* qp = pred + (size_t)b * 4 * C + (size_t)cls * 4;
    const float* qg = tgt  + (size_t)b * 4 * C + (size_t)cls * 4;
    const float pw = qp[0], px = qp[1], py = qp[2], pz = qp[3];
    const float gw = qg[0], gx = qg[1], gy = qg[2], gz = qg[3];
    float dot = fabsf(pw * gw + px * gx + py * gy + pz * gz);
    dot = fminf(fmaxf(dot, 0.0f), 1.0f);
    const bool uc = (sym[cls] > 0.0f) && (dot < HARD_COS);

    const float4* prb = (const float4*)ws + (size_t)b * NPTS;
    const float4* gtb = (const float4*)(ws + (size_t)gt_off) + (size_t)b * NPTS;

    const int pA = blockIdx.x * PPB + lane;      // same across all 4 waves
    const int pB = pA + 64;
    const float4 ppA = prb[pA];
    const float4 ppB = prb[pB];

    float acc = 0.0f;
    if (uc) {
        // stage whole gt cloud (coalesced)
#pragma unroll
        for (int r = 0; r < 8; ++r) gls[r * 256 + tid] = gtb[r * 256 + tid];
        __syncthreads();

        const int jb = (tid >> 6) * 512;         // this wave's gt quarter
        const float nxA = -2.f * ppA.x, nyA = -2.f * ppA.y, nzA = -2.f * ppA.z;
        const float nxB = -2.f * ppB.x, nyB = -2.f * ppB.y, nzB = -2.f * ppB.z;
        float bdA = 3.4e38f, bdB = 3.4e38f;
        int bjA = jb, bjB = jb;
#pragma unroll 8
        for (int j = 0; j < 512; ++j) {
            const float4 g = gls[jb + j];        // wave-uniform -> broadcast
            float dA = __fmaf_rn(nxA, g.x, __fmaf_rn(nyA, g.y, __fmaf_rn(nzA, g.z, g.w)));
            float dB = __fmaf_rn(nxB, g.x, __fmaf_rn(nyB, g.y, __fmaf_rn(nzB, g.z, g.w)));
            if (dA < bdA) { bdA = dA; bjA = jb + j; }   // strict <: first min
            if (dB < bdB) { bdB = dB; bjB = jb + j; }
        }
        sbd[tid] = bdA;       sbj[tid] = bjA;
        sbd[tid + 256] = bdB; sbj[tid + 256] = bjB;
        __syncthreads();

        if (tid < 64) {
            float bd1 = sbd[lane];       int bj1 = sbj[lane];
            float bd2 = sbd[256 + lane]; int bj2 = sbj[256 + lane];
#pragma unroll
            for (int w = 1; w < 4; ++w) {        // ascending quarters, strict <
                float d1 = sbd[w * 64 + lane];
                if (d1 < bd1) { bd1 = d1; bj1 = sbj[w * 64 + lane]; }
                float d2 = sbd[256 + w * 64 + lane];
                if (d2 < bd2) { bd2 = d2; bj2 = sbj[256 + w * 64 + lane]; }
            }
            const float4 g1 = gtb[bj1];
            const float4 g2 = gtb[bj2];
            acc = smooth_l1(ppA.x - g1.x) + smooth_l1(ppA.y - g1.y) + smooth_l1(ppA.z - g1.z)
                + smooth_l1(ppB.x - g2.x) + smooth_l1(ppB.y - g2.y) + smooth_l1(ppB.z - g2.z);
        }
    } else {
        if (tid < 64) {
            const float4 g1 = gtb[pA];
            const float4 g2 = gtb[pB];
            acc = smooth_l1(ppA.x - g1.x) + smooth_l1(ppA.y - g1.y) + smooth_l1(ppA.z - g1.z)
                + smooth_l1(ppB.x - g2.x) + smooth_l1(ppB.y - g2.y) + smooth_l1(ppB.z - g2.z);
        }
    }

    if (tid < 64) {                              // wave 0 only
        for (int off = 32; off > 0; off >>= 1) acc += __shfl_down(acc, off);
        if (tid == 0) atomicAdd(out, acc * inv_bp);
    }
}

extern "C" void kernel_launch(void* const* d_in, const int* in_sizes, int n_in,
                              void* d_out, int out_size, void* d_ws, size_t ws_size,
                              hipStream_t stream) {
    const float* pred = (const float*)d_in[0];
    const float* tgt  = (const float*)d_in[1];
    const float* wgt  = (const float*)d_in[2];
    const float* pts  = (const float*)d_in[3];
    const float* sym  = (const float*)d_in[4];
    float* out = (float*)d_out;
    float* ws  = (float*)d_ws;

    const int C = in_sizes[4];
    const int B = in_sizes[0] / (4 * C);
    const int gt_off = B * NPTS * 4;             // floats

    dim3 gridR(2, B);
    pm_rot<<<gridR, 256, 0, stream>>>(pred, tgt, wgt, pts, ws, out, C, gt_off);
    dim3 gridS(NPTS / PPB, B);
    pm_scan<<<gridS, 256, 0, stream>>>(pred, tgt, wgt, sym, ws, out, C, gt_off,
                                       1.0f / (float)(B * NPTS));
}